// Round 4
// baseline (1417.090 us; speedup 1.0000x reference)
//
#include <hip/hip_runtime.h>
#include <hip/hip_bf16.h>

#define D_DIM 512
#define S_LEN 12
#define H_NUM 8
#define G_B 4
#define ROWS 48           // G_B * S_LEN = 3 M-tiles
#define THREADS 256       // 4 waves
#define WMAT 262144       // 512*512

// smem byte offsets (all tiles XOR-swizzled, no padding)
#define X_OFF   0                 // [48][512] bf16, row stride 1024B
#define Q_OFF   49152             // [48][64] bf16, row stride 128B
#define K_OFF   55296
#define V_OFF   61440
#define A_OFF   67584
#define P_OFF   73728             // [4][12][20] f32 ; union: red [48][9] f32
#define MU_OFF  77568             // [48][2] f32
#define SMEM_BYTES 77952          // x2 = 155,904 <= 160 KiB -> 2 blocks/CU

typedef __attribute__((ext_vector_type(8))) short bf16x8;
typedef __attribute__((ext_vector_type(4))) float f32x4;

__device__ __forceinline__ unsigned short f2bf(float f) {
    union { float f; unsigned u; } c; c.f = f;
    unsigned r = c.u + 0x7fffu + ((c.u >> 16) & 1u);
    return (unsigned short)(r >> 16);
}
__device__ __forceinline__ float bf2f(unsigned short u) {
    union { unsigned u; float f; } c; c.u = ((unsigned)u) << 16;
    return c.f;
}
// 16B-granule XOR swizzle: chunk (8 bf16) index ^= row&7. col's low 3 bits untouched.
__device__ __forceinline__ int xswc(int row, int col) {  // X tile: 512 cols
    return row * 512 + (((col >> 3) ^ (row & 7)) << 3) + (col & 7);
}
__device__ __forceinline__ int qsw(int row, int col) {   // QKVA tiles: 64 cols
    return row * 64 + (((col >> 3) ^ (row & 7)) << 3) + (col & 7);
}

__global__ void prep_weights(const float* __restrict__ Wq, const float* __restrict__ Wk,
                             const float* __restrict__ Wv, const float* __restrict__ Wo,
                             unsigned short* __restrict__ wt) {
    int idx = blockIdx.x * 256 + threadIdx.x;   // 0 .. 4*WMAT-1
    int mat = idx >> 18;
    int rem = idx & (WMAT - 1);
    int e = rem >> 9, d = rem & 511;
    const float* W = (mat == 0) ? Wq : (mat == 1) ? Wk : (mat == 2) ? Wv : Wo;
    wt[idx] = f2bf(W[d * D_DIM + e]);           // wt[mat][e][d] = W[d][e]
}

__global__ __launch_bounds__(THREADS, 2) void fused_attn(
    const float* __restrict__ x, const unsigned short* __restrict__ wt,
    const float* __restrict__ bq, const float* __restrict__ bk, const float* __restrict__ bv,
    const float* __restrict__ adj, const float* __restrict__ bo,
    const float* __restrict__ gamma, const float* __restrict__ beta,
    float* __restrict__ out)
{
    extern __shared__ char smem[];
    unsigned short* Xh = (unsigned short*)(smem + X_OFF);
    unsigned short* Qh = (unsigned short*)(smem + Q_OFF);
    unsigned short* Kh = (unsigned short*)(smem + K_OFF);
    unsigned short* Vh = (unsigned short*)(smem + V_OFF);
    unsigned short* Ah = (unsigned short*)(smem + A_OFF);
    float* Pl    = (float*)(smem + P_OFF);      // [4][12][20]
    float* red   = (float*)(smem + P_OFF);      // [48][9] (time-disjoint union)
    float* musig = (float*)(smem + MU_OFF);     // [48][2]

    const int tid  = threadIdx.x;
    const int lane = tid & 63;
    const int w    = tid >> 6;          // wave 0..3
    const int lr   = lane & 15;
    const int lg   = lane >> 4;
    const size_t row0 = (size_t)blockIdx.x * ROWS;

    // ---------------- phase 0: stage X -> LDS bf16 (swizzled) ----------------
    #pragma unroll
    for (int it = 0; it < 24; ++it) {
        int idx = it * THREADS + tid;            // 6144 chunks of 4 floats
        int r = idx >> 7, col = (idx & 127) << 2;
        float4 v = *(const float4*)(x + (row0 + r) * (size_t)D_DIM + col);
        ushort4 pk;
        pk.x = f2bf(v.x); pk.y = f2bf(v.y); pk.z = f2bf(v.z); pk.w = f2bf(v.w);
        *(ushort4*)(Xh + xswc(r, col)) = pk;
    }
    __syncthreads();

    // persistent out-proj accumulators: wave w owns cols [w*128, w*128+128)
    f32x4 Y[3][8];
    #pragma unroll
    for (int mt = 0; mt < 3; ++mt)
        #pragma unroll
        for (int nt = 0; nt < 8; ++nt) Y[mt][nt] = (f32x4){0.f, 0.f, 0.f, 0.f};

    const float* bptr[3] = {bq, bk, bv};
    const int colh = w * 16 + lr;                // wave's QKV col within head
    const int rb = w * S_LEN;                    // wave's batch rows
    const int lr12 = (lr < 12) ? lr : 11;        // TRUE clamp (lr&11 mangled lanes 4-7!)

    for (int h = 0; h < H_NUM; ++h) {
        // ---------------- QKV projection for head h ----------------
        f32x4 acc[3][3];
        #pragma unroll
        for (int a = 0; a < 3; ++a)
            #pragma unroll
            for (int b2 = 0; b2 < 3; ++b2) acc[a][b2] = (f32x4){0.f, 0.f, 0.f, 0.f};

        const unsigned short* wbase = wt + (h * 64 + colh) * D_DIM;
        #pragma unroll
        for (int ks = 0; ks < 16; ++ks) {
            bf16x8 af[3];
            #pragma unroll
            for (int mt = 0; mt < 3; ++mt)
                af[mt] = *(const bf16x8*)(Xh + xswc(mt * 16 + lr, ks * 32 + lg * 8));
            #pragma unroll
            for (int mat = 0; mat < 3; ++mat) {
                bf16x8 bf = *(const bf16x8*)(wbase + mat * WMAT + ks * 32 + lg * 8);
                #pragma unroll
                for (int mt = 0; mt < 3; ++mt)
                    acc[mat][mt] = __builtin_amdgcn_mfma_f32_16x16x32_bf16(af[mt], bf, acc[mat][mt], 0, 0, 0);
            }
        }
        #pragma unroll
        for (int mat = 0; mat < 3; ++mat) {
            float bias = bptr[mat][h * 64 + colh];
            unsigned short* T = (mat == 0) ? Qh : (mat == 1) ? Kh : Vh;
            #pragma unroll
            for (int mt = 0; mt < 3; ++mt)
                #pragma unroll
                for (int j = 0; j < 4; ++j)
                    T[qsw(mt * 16 + lg * 4 + j, colh)] = f2bf(acc[mat][mt][j] + bias);
        }
        __syncthreads();

        // ---------------- attention (wave w <-> batch w) ----------------
        f32x4 sacc = (f32x4){0.f, 0.f, 0.f, 0.f};
        #pragma unroll
        for (int ks = 0; ks < 2; ++ks) {
            bf16x8 ak = *(const bf16x8*)(Kh + qsw(rb + lr12, ks * 32 + lg * 8));
            bf16x8 aq = *(const bf16x8*)(Qh + qsw(rb + lr12, ks * 32 + lg * 8));
            sacc = __builtin_amdgcn_mfma_f32_16x16x32_bf16(ak, aq, sacc, 0, 0, 0);
        }
        float ab4[4] = {0.f, 0.f, 0.f, 0.f};
        if (lg < 3 && lr < 12) {
            float4 t4 = *(const float4*)(adj + (h * S_LEN + lr) * S_LEN + lg * 4);
            ab4[0] = t4.x; ab4[1] = t4.y; ab4[2] = t4.z; ab4[3] = t4.w;
        }
        float sc[4], e4[4];
        float m = -1e30f;
        #pragma unroll
        for (int j = 0; j < 4; ++j) {
            int t = lg * 4 + j;
            sc[j] = (t < 12) ? (sacc[j] * 0.125f + ab4[j]) : -1e30f;
            m = fmaxf(m, sc[j]);
        }
        m = fmaxf(m, __shfl_xor(m, 16));
        m = fmaxf(m, __shfl_xor(m, 32));
        float ssum = 0.f;
        #pragma unroll
        for (int j = 0; j < 4; ++j) { e4[j] = __expf(sc[j] - m); ssum += e4[j]; }
        ssum += __shfl_xor(ssum, 16);
        ssum += __shfl_xor(ssum, 32);
        float inv = 1.f / ssum;
        float* Pw = Pl + w * 240;
        // type-consistent f32x4 store (matches the f32x4 reads below); lg==3 holds
        // only masked t>=12 columns, so only lg<3 stores are needed.
        if (lr < 12 && lg < 3) {
            f32x4 pvec = (f32x4){e4[0] * inv, e4[1] * inv, e4[2] * inv, e4[3] * inv};
            *(f32x4*)(Pw + lr * 20 + lg * 4) = pvec;
        }
        __syncthreads();

        // ---------------- PV: lane = dim d (0..63); P broadcast from LDS ----------------
        {
            float vv[12];
            #pragma unroll
            for (int t = 0; t < 12; ++t) vv[t] = bf2f(Vh[qsw(rb + t, lane)]);
            #pragma unroll
            for (int ss = 0; ss < 12; ++ss) {
                f32x4 pa = *(const f32x4*)(Pw + ss * 20);
                f32x4 pb = *(const f32x4*)(Pw + ss * 20 + 4);
                f32x4 pc = *(const f32x4*)(Pw + ss * 20 + 8);
                float o = 0.f;
                #pragma unroll
                for (int t = 0; t < 4; ++t) o += pa[t] * vv[t];
                #pragma unroll
                for (int t = 0; t < 4; ++t) o += pb[t] * vv[4 + t];
                #pragma unroll
                for (int t = 0; t < 4; ++t) o += pc[t] * vv[8 + t];
                Ah[qsw(rb + ss, lane)] = f2bf(o);
            }
        }
        __syncthreads();

        // ---------------- out-projection accumulate (K-slice = head h) ----------------
        const unsigned short* obase = wt + 3 * WMAT + (w * 128 + lr) * D_DIM + h * 64;
        #pragma unroll
        for (int ks = 0; ks < 2; ++ks) {
            bf16x8 afr[3];
            #pragma unroll
            for (int mt = 0; mt < 3; ++mt)
                afr[mt] = *(const bf16x8*)(Ah + qsw(mt * 16 + lr, ks * 32 + lg * 8));
            #pragma unroll
            for (int nt = 0; nt < 8; ++nt) {
                bf16x8 bfr = *(const bf16x8*)(obase + nt * 16 * D_DIM + ks * 32 + lg * 8);
                #pragma unroll
                for (int mt = 0; mt < 3; ++mt)
                    Y[mt][nt] = __builtin_amdgcn_mfma_f32_16x16x32_bf16(afr[mt], bfr, Y[mt][nt], 0, 0, 0);
            }
        }
        // no trailing barrier: next QKV phase writes Q/K/V which were last read
        // before this head's post-P barrier; Ah is next written after the next
        // post-QKV barrier.
    }

    // ---------------- epilogue: +bo, +x (fp32), LayerNorm, store ----------------
    float bo8[8], gm8[8], bt8[8];
    int cols[8];
    #pragma unroll
    for (int nt = 0; nt < 8; ++nt) {
        cols[nt] = w * 128 + nt * 16 + lr;
        bo8[nt] = bo[cols[nt]]; gm8[nt] = gamma[cols[nt]]; bt8[nt] = beta[cols[nt]];
    }
    #pragma unroll
    for (int mt = 0; mt < 3; ++mt)
        #pragma unroll
        for (int j = 0; j < 4; ++j) {
            int rowl = mt * 16 + lg * 4 + j;
            const float* xrow = x + (row0 + rowl) * (size_t)D_DIM;
            float ps = 0.f, pq = 0.f;
            #pragma unroll
            for (int nt = 0; nt < 8; ++nt) {
                float y = Y[mt][nt][j] + bo8[nt] + xrow[cols[nt]];
                Y[mt][nt][j] = y;
                ps += y; pq += y * y;
            }
            ps += __shfl_xor(ps, 1); pq += __shfl_xor(pq, 1);
            ps += __shfl_xor(ps, 2); pq += __shfl_xor(pq, 2);
            ps += __shfl_xor(ps, 4); pq += __shfl_xor(pq, 4);
            ps += __shfl_xor(ps, 8); pq += __shfl_xor(pq, 8);
            if (lr == 0) { red[rowl * 9 + w * 2] = ps; red[rowl * 9 + w * 2 + 1] = pq; }
        }
    __syncthreads();
    if (tid < ROWS) {
        float s = 0.f, q = 0.f;
        #pragma unroll
        for (int w4 = 0; w4 < 4; ++w4) { s += red[tid * 9 + w4 * 2]; q += red[tid * 9 + w4 * 2 + 1]; }
        float mu = s * (1.f / 512.f);
        float var = q * (1.f / 512.f) - mu * mu;
        musig[tid * 2] = mu;
        musig[tid * 2 + 1] = rsqrtf(var + 1e-5f);
    }
    __syncthreads();
    #pragma unroll
    for (int mt = 0; mt < 3; ++mt)
        #pragma unroll
        for (int j = 0; j < 4; ++j) {
            int rowl = mt * 16 + lg * 4 + j;
            float mu = musig[rowl * 2], rs = musig[rowl * 2 + 1];
            float* orow = out + (row0 + rowl) * (size_t)D_DIM;
            #pragma unroll
            for (int nt = 0; nt < 8; ++nt)
                orow[cols[nt]] = (Y[mt][nt][j] - mu) * rs * gm8[nt] + bt8[nt];
        }
}

extern "C" void kernel_launch(void* const* d_in, const int* in_sizes, int n_in,
                              void* d_out, int out_size, void* d_ws, size_t ws_size,
                              hipStream_t stream) {
    (void)in_sizes; (void)n_in; (void)out_size; (void)ws_size;
    const float* x     = (const float*)d_in[0];
    const float* Wq    = (const float*)d_in[1];
    const float* bq    = (const float*)d_in[2];
    const float* Wk    = (const float*)d_in[3];
    const float* bk    = (const float*)d_in[4];
    const float* Wv    = (const float*)d_in[5];
    const float* bv    = (const float*)d_in[6];
    const float* adj   = (const float*)d_in[7];
    const float* Wo    = (const float*)d_in[8];
    const float* bo    = (const float*)d_in[9];
    const float* gamma = (const float*)d_in[10];
    const float* beta  = (const float*)d_in[11];
    unsigned short* wt = (unsigned short*)d_ws;      // 4 * 512*512 bf16 = 2 MiB

    prep_weights<<<4096, 256, 0, stream>>>(Wq, Wk, Wv, Wo, wt);
    fused_attn<<<16384 / G_B, THREADS, SMEM_BYTES, stream>>>(
        x, wt, bq, bk, bv, adj, bo, gamma, beta, (float*)d_out);
}